// Round 1
// baseline (678.031 us; speedup 1.0000x reference)
//
#include <hip/hip_runtime.h>

typedef __attribute__((ext_vector_type(8))) short bf16x8;
typedef __attribute__((ext_vector_type(4))) float f32x4;

#define NPTS 262144
#define PTS_PER_BLK 128
#define TPB 512

__device__ __forceinline__ unsigned short f2bf(float f) {
  unsigned int u = __float_as_uint(f);
  u += 0x7fffu + ((u >> 16) & 1u);
  return (unsigned short)(u >> 16);
}
__device__ __forceinline__ float bf2f(unsigned short s) {
  return __uint_as_float(((unsigned int)s) << 16);
}

// ---------- prep: convert weights to MFMA fragment layout (bf16) ----------
// frag layout: dst[((nb*KB + kb)*64 + lane)*8 + i] = W[nb*16 + (lane&15)][kb*32 + (lane>>4)*8 + i]
// (zero-padded for k >= KIN).  trans=1 reads src[k*OUTD + row] (for gfeat^T).
__global__ void prep_w(const float* __restrict__ src, unsigned short* __restrict__ dst,
                       int KIN, int KB, int trans, int OUTD, int total) {
  int idx = blockIdx.x * blockDim.x + threadIdx.x;
  if (idx >= total) return;
  int i = idx & 7;
  int l = (idx >> 3) & 63;
  int t = idx >> 9;
  int kb = t % KB, nb = t / KB;
  int row = nb * 16 + (l & 15);
  int k = kb * 32 + (l >> 4) * 8 + i;
  float v = 0.0f;
  if (k < KIN) v = trans ? src[k * OUTD + row] : src[row * KIN + k];
  dst[idx] = f2bf(v);
}

// gaussian params: [g][8] = cx,cy,cz, 1/d0,1/d1,1/d2, coeff, 0
__global__ void prep_gauss(const float* __restrict__ centers, const float* __restrict__ cov,
                           float* __restrict__ gp) {
  int g = threadIdx.x;
  if (g >= 128) return;
  float c0 = cov[g * 9 + 0], c1 = cov[g * 9 + 4], c2 = cov[g * 9 + 8];
  float det = c0 * c1 * c2;
  float coeff = 1.0f / (15.749609945722419f * sqrtf(det));  // (2*pi)^1.5 * sqrt(det)
  gp[g * 8 + 0] = centers[g * 3 + 0];
  gp[g * 8 + 1] = centers[g * 3 + 1];
  gp[g * 8 + 2] = centers[g * 3 + 2];
  gp[g * 8 + 3] = 1.0f / c0;
  gp[g * 8 + 4] = 1.0f / c1;
  gp[g * 8 + 5] = 1.0f / c2;
  gp[g * 8 + 6] = coeff;
  gp[g * 8 + 7] = 0.0f;
}

// ---------- main fused kernel ----------
// LDS: h[pt][col] bf16, 128 pts x 512 cols, byte = pt*1024 + col*2, XOR-swizzled by ((pt&7)<<4).
// One wave = 64 neurons x 128 pts. A-operand = weights (frag layout from global),
// B-operand = activations (ds_read_b128).  D: col(lane&15)=pt, row((lane>>4)*4+r)=neuron.

template <int KB, int ACT>  // ACT: 0=none 1=lrelu(0.2) 2=sin(30x)
__device__ __forceinline__ void mlp_layer(const unsigned short* __restrict__ wf,
                                          const float* __restrict__ bias,
                                          char* hb, int lane, int wid) {
  const int r8 = lane >> 4, l15 = lane & 15;
  f32x4 acc[4][8];
#pragma unroll
  for (int a0 = 0; a0 < 4; ++a0)
#pragma unroll
    for (int b0 = 0; b0 < 8; ++b0)
      acc[a0][b0] = (f32x4){0.f, 0.f, 0.f, 0.f};

  const unsigned short* wbase = wf + wid * 4 * KB * 512 + lane * 8;
#pragma unroll 4
  for (int kb = 0; kb < KB; ++kb) {
    bf16x8 a[4];
#pragma unroll
    for (int nf = 0; nf < 4; ++nf)
      a[nf] = *(const bf16x8*)(wbase + (nf * KB + kb) * 512);
    bf16x8 b[8];
#pragma unroll
    for (int pf = 0; pf < 8; ++pf) {
      int pt = pf * 16 + l15;
      int off = (pt * 1024 + kb * 64 + r8 * 16) ^ ((pt & 7) << 4);
      b[pf] = *(const bf16x8*)(hb + off);
    }
#pragma unroll
    for (int nf = 0; nf < 4; ++nf)
#pragma unroll
      for (int pf = 0; pf < 8; ++pf)
        acc[nf][pf] = __builtin_amdgcn_mfma_f32_16x16x32_bf16(a[nf], b[pf], acc[nf][pf], 0, 0, 0);
  }
  __syncthreads();  // all reads of h done before overwrite
#pragma unroll
  for (int nf = 0; nf < 4; ++nf) {
    int n0 = wid * 64 + nf * 16 + r8 * 4;
    f32x4 bv = *(const f32x4*)(bias + n0);
#pragma unroll
    for (int pf = 0; pf < 8; ++pf) {
      int pt = pf * 16 + l15;
      float v[4];
#pragma unroll
      for (int r = 0; r < 4; ++r) {
        float z = acc[nf][pf][r] + bv[r];
        if (ACT == 1) z = (z > 0.f) ? z : 0.2f * z;
        else if (ACT == 2) z = __sinf(30.f * z);
        v[r] = z;
      }
      unsigned long long pk =
          (unsigned long long)((unsigned int)f2bf(v[0]) | ((unsigned int)f2bf(v[1]) << 16)) |
          ((unsigned long long)((unsigned int)f2bf(v[2]) | ((unsigned int)f2bf(v[3]) << 16)) << 32);
      int off = (pt * 1024 + n0 * 2) ^ ((pt & 7) << 4);
      *(unsigned long long*)(hb + off) = pk;
    }
  }
  __syncthreads();
}

__global__ __launch_bounds__(TPB, 2) void gmminr_main(
    const float* __restrict__ x,
    const float* __restrict__ b1, const float* __restrict__ b2,
    const float* __restrict__ b3, const float* __restrict__ b4,
    const float* __restrict__ w5, const float* __restrict__ b5,
    const unsigned short* __restrict__ wf1, const unsigned short* __restrict__ wf2,
    const unsigned short* __restrict__ wf3, const unsigned short* __restrict__ wf4,
    const unsigned short* __restrict__ gff, const float* __restrict__ gp,
    float* __restrict__ out) {
  __shared__ char hb[PTS_PER_BLK * 1024];
  const int tid = threadIdx.x;
  const int lane = tid & 63;
  const int wid = tid >> 6;
  const int pt0 = blockIdx.x * PTS_PER_BLK;

  // ---------------- stage: dens (cols 256..383), pe (128..175), zero-pad (176..191)
  {
    const int pt = tid >> 2;
    const int q = tid & 3;
    const float X = x[(pt0 + pt) * 3 + 0];
    const float Y = x[(pt0 + pt) * 3 + 1];
    const float Z = x[(pt0 + pt) * 3 + 2];
#pragma unroll 2
    for (int j = 0; j < 32; j += 4) {
      float d4[4];
#pragma unroll
      for (int e = 0; e < 4; ++e) {
        const float* P = gp + (q * 32 + j + e) * 8;
        float dx = X - P[0], dy = Y - P[1], dz = Z - P[2];
        float m = dx * dx * P[3] + dy * dy * P[4] + dz * dz * P[5];
        d4[e] = P[6] * __expf(-0.5f * m);
      }
      unsigned long long pk =
          (unsigned long long)((unsigned int)f2bf(d4[0]) | ((unsigned int)f2bf(d4[1]) << 16)) |
          ((unsigned long long)((unsigned int)f2bf(d4[2]) | ((unsigned int)f2bf(d4[3]) << 16)) << 32);
      int col = 256 + q * 32 + j;
      int off = (pt * 1024 + col * 2) ^ ((pt & 7) << 4);
      *(unsigned long long*)(hb + off) = pk;
    }
    // positional encoding: col 128 + l*6 + d (sin), +3 (cos); thread q does l = 2q, 2q+1
    float co[3] = {X, Y, Z};
#pragma unroll
    for (int lg = 0; lg < 2; ++lg) {
      int le = q * 2 + lg;
      float fr = 3.14159265358979323846f * (float)(1 << le);
#pragma unroll
      for (int d = 0; d < 3; ++d) {
        float arg = fr * co[d];
        float s = __sinf(arg), c = __cosf(arg);
        int cs = 128 + le * 6 + d;
        *(unsigned short*)(hb + ((pt * 1024 + cs * 2) ^ ((pt & 7) << 4))) = f2bf(s);
        *(unsigned short*)(hb + ((pt * 1024 + (cs + 3) * 2) ^ ((pt & 7) << 4))) = f2bf(c);
      }
    }
    {
      int col = 176 + q * 4;
      int off = (pt * 1024 + col * 2) ^ ((pt & 7) << 4);
      *(unsigned long long*)(hb + off) = 0ull;
    }
  }
  __syncthreads();

  // ---------------- feat = dens @ gfeat  -> cols 0..127 (wave = 16 F-rows x 128 pts)
  {
    const int r8 = lane >> 4, l15 = lane & 15;
    f32x4 facc[8];
#pragma unroll
    for (int pf = 0; pf < 8; ++pf) facc[pf] = (f32x4){0.f, 0.f, 0.f, 0.f};
    const unsigned short* gbase = gff + wid * 4 * 512 + lane * 8;
#pragma unroll
    for (int kb = 0; kb < 4; ++kb) {
      bf16x8 a = *(const bf16x8*)(gbase + kb * 512);
#pragma unroll
      for (int pf = 0; pf < 8; ++pf) {
        int pt = pf * 16 + l15;
        int off = (pt * 1024 + 512 + kb * 64 + r8 * 16) ^ ((pt & 7) << 4);
        bf16x8 b = *(const bf16x8*)(hb + off);
        facc[pf] = __builtin_amdgcn_mfma_f32_16x16x32_bf16(a, b, facc[pf], 0, 0, 0);
      }
    }
    int f0 = wid * 16 + r8 * 4;
#pragma unroll
    for (int pf = 0; pf < 8; ++pf) {
      int pt = pf * 16 + l15;
      unsigned long long pk =
          (unsigned long long)((unsigned int)f2bf(facc[pf][0]) | ((unsigned int)f2bf(facc[pf][1]) << 16)) |
          ((unsigned long long)((unsigned int)f2bf(facc[pf][2]) | ((unsigned int)f2bf(facc[pf][3]) << 16)) << 32);
      int off = (pt * 1024 + f0 * 2) ^ ((pt & 7) << 4);
      *(unsigned long long*)(hb + off) = pk;
    }
  }
  __syncthreads();

  // ---------------- MLP
  mlp_layer<6, 1>(wf1, b1, hb, lane, wid);    // 176(pad192) -> 512, leaky relu
  mlp_layer<16, 2>(wf2, b2, hb, lane, wid);   // sin(30x)
  mlp_layer<16, 2>(wf3, b3, hb, lane, wid);
  mlp_layer<16, 2>(wf4, b4, hb, lane, wid);

  // ---------------- final: out[pt] = h4 . w5 + b5
  {
    const int pt = tid >> 2, q = tid & 3;
    float s = 0.f;
#pragma unroll 4
    for (int kk = 0; kk < 128; kk += 8) {
      int k = q * 128 + kk;
      int off = (pt * 1024 + k * 2) ^ ((pt & 7) << 4);
      bf16x8 hv = *(const bf16x8*)(hb + off);
      f32x4 w0 = *(const f32x4*)(w5 + k);
      f32x4 w1 = *(const f32x4*)(w5 + k + 4);
#pragma unroll
      for (int e = 0; e < 4; ++e) s += bf2f((unsigned short)hv[e]) * w0[e];
#pragma unroll
      for (int e = 0; e < 4; ++e) s += bf2f((unsigned short)hv[4 + e]) * w1[e];
    }
    s += __shfl_down(s, 2, 4);
    s += __shfl_down(s, 1, 4);
    if (q == 0) out[pt0 + pt] = s + b5[0];
  }
}

extern "C" void kernel_launch(void* const* d_in, const int* in_sizes, int n_in,
                              void* d_out, int out_size, void* d_ws, size_t ws_size,
                              hipStream_t stream) {
  const float* x   = (const float*)d_in[0];
  const float* cen = (const float*)d_in[1];
  const float* cov = (const float*)d_in[2];
  const float* gfe = (const float*)d_in[3];
  const float* W1  = (const float*)d_in[4];
  const float* b1  = (const float*)d_in[5];
  const float* W2  = (const float*)d_in[6];
  const float* b2  = (const float*)d_in[7];
  const float* W3  = (const float*)d_in[8];
  const float* b3  = (const float*)d_in[9];
  const float* W4  = (const float*)d_in[10];
  const float* b4  = (const float*)d_in[11];
  const float* W5  = (const float*)d_in[12];
  const float* b5  = (const float*)d_in[13];
  float* out = (float*)d_out;

  char* ws = (char*)d_ws;
  unsigned short* wf1 = (unsigned short*)(ws);             // 32*6*512  = 98304  el (192KB)
  unsigned short* wf2 = (unsigned short*)(ws + 196608);    // 32*16*512 = 262144 el (512KB)
  unsigned short* wf3 = (unsigned short*)(ws + 720896);
  unsigned short* wf4 = (unsigned short*)(ws + 1245184);
  unsigned short* gff = (unsigned short*)(ws + 1769472);   // 8*4*512 = 16384 el (32KB)
  float* gp = (float*)(ws + 1802240);                      // 128*8 f32 (4KB)

  prep_w<<<98304 / 256, 256, 0, stream>>>(W1, wf1, 176, 6, 0, 512, 98304);
  prep_w<<<262144 / 256, 256, 0, stream>>>(W2, wf2, 512, 16, 0, 512, 262144);
  prep_w<<<262144 / 256, 256, 0, stream>>>(W3, wf3, 512, 16, 0, 512, 262144);
  prep_w<<<262144 / 256, 256, 0, stream>>>(W4, wf4, 512, 16, 0, 512, 262144);
  prep_w<<<16384 / 256, 256, 0, stream>>>(gfe, gff, 128, 4, 1, 128, 16384);
  prep_gauss<<<1, 128, 0, stream>>>(cen, cov, gp);

  gmminr_main<<<NPTS / PTS_PER_BLK, TPB, 0, stream>>>(
      x, b1, b2, b3, b4, W5, b5, wf1, wf2, wf3, wf4, gff, gp, out);
}

// Round 6
// 582.776 us; speedup vs baseline: 1.1634x; 1.1634x over previous
//
#include <hip/hip_runtime.h>

typedef __attribute__((ext_vector_type(8))) short bf16x8;
typedef __attribute__((ext_vector_type(4))) float f32x4;

#define NPTS 262144
#define PTS_PER_BLK 64
#define TPB 512
#define NBLK (NPTS / PTS_PER_BLK)

__device__ __forceinline__ unsigned short f2bf(float f) {
  unsigned int u = __float_as_uint(f);
  u += 0x7fffu + ((u >> 16) & 1u);
  return (unsigned short)(u >> 16);
}
__device__ __forceinline__ unsigned int pklo(float a, float b) {
  return (unsigned int)f2bf(a) | ((unsigned int)f2bf(b) << 16);
}
__device__ __forceinline__ unsigned long long pk4(float a, float b, float c, float d) {
  return (unsigned long long)pklo(a, b) | ((unsigned long long)pklo(c, d) << 32);
}

// ---------- prep: weights -> 16x16x32 MFMA A-fragment layout (bf16), round-1 verified ----------
// dst[((nb*KB + kb)*64 + l)*8 + i] = W[nb*16 + (l&15)][kb*32 + (l>>4)*8 + i]
__global__ void prep_w(const float* __restrict__ src, unsigned short* __restrict__ dst,
                       int KIN, int KB, int trans, int OUTD, int total) {
  int idx = blockIdx.x * blockDim.x + threadIdx.x;
  if (idx >= total) return;
  int i = idx & 7;
  int l = (idx >> 3) & 63;
  int t = idx >> 9;
  int kb = t % KB, nb = t / KB;
  int row = nb * 16 + (l & 15);
  int k = kb * 32 + (l >> 4) * 8 + i;
  float v = 0.0f;
  if (k < KIN) v = trans ? src[k * OUTD + row] : src[row * KIN + k];
  dst[idx] = f2bf(v);
}

// gaussian params: [g][8] = cx,cy,cz, 1/d0,1/d1,1/d2, coeff, 0
__global__ void prep_gauss(const float* __restrict__ centers, const float* __restrict__ cov,
                           float* __restrict__ gp) {
  int g = threadIdx.x;
  if (g >= 128) return;
  float c0 = cov[g * 9 + 0], c1 = cov[g * 9 + 4], c2 = cov[g * 9 + 8];
  float det = c0 * c1 * c2;
  float coeff = 1.0f / (15.749609945722419f * sqrtf(det));  // (2*pi)^1.5 * sqrt(det)
  gp[g * 8 + 0] = centers[g * 3 + 0];
  gp[g * 8 + 1] = centers[g * 3 + 1];
  gp[g * 8 + 2] = centers[g * 3 + 2];
  gp[g * 8 + 3] = 1.0f / c0;
  gp[g * 8 + 4] = 1.0f / c1;
  gp[g * 8 + 5] = 1.0f / c2;
  gp[g * 8 + 6] = coeff;
  gp[g * 8 + 7] = 0.0f;
}

__global__ void prep_scale(const float* __restrict__ src, float* __restrict__ dst, int n) {
  int i = blockIdx.x * blockDim.x + threadIdx.x;
  if (i < n) dst[i] = src[i] * 30.0f;
}

// ---------- main fused kernel ----------
// LDS: h[pt][col] bf16, 64 pts x 512 cols, byte = pt*1024 + col*2, XOR ((pt&7)<<4).
// 8 waves, each owns 64 neurons (nf 0..3) x all 64 pts (pf 0..3).
// MFMA 16x16x32 (round-1 verified layouts): A=weights frag (global/L2), B=acts (ds_read_b128).
// D: col = lane&15 = pt, row = (lane>>4)*4 + reg = neuron-within-16.

template <int KB, int ACT>  // ACT: 1=lrelu(0.2) raw bias; 2=sin with bias pre-scaled x30
__device__ __forceinline__ void mlp_layer(const unsigned short* __restrict__ wf,
                                          const float* __restrict__ bias,
                                          char* hb, int lane, int wid) {
  const int r8 = lane >> 4, l15 = lane & 15;
  f32x4 acc[4][4];
#pragma unroll
  for (int a0 = 0; a0 < 4; ++a0)
#pragma unroll
    for (int b0 = 0; b0 < 4; ++b0)
      acc[a0][b0] = (f32x4){0.f, 0.f, 0.f, 0.f};

  const unsigned short* wbase = wf + wid * 4 * KB * 512 + lane * 8;
#pragma unroll 2
  for (int kb = 0; kb < KB; ++kb) {
    bf16x8 a[4];
#pragma unroll
    for (int nf = 0; nf < 4; ++nf)
      a[nf] = *(const bf16x8*)(wbase + (nf * KB + kb) * 512);
    bf16x8 b[4];
#pragma unroll
    for (int pf = 0; pf < 4; ++pf) {
      int pt = pf * 16 + l15;
      int off = (pt * 1024 + kb * 64 + r8 * 16) ^ ((pt & 7) << 4);
      b[pf] = *(const bf16x8*)(hb + off);
    }
#pragma unroll
    for (int nf = 0; nf < 4; ++nf)
#pragma unroll
      for (int pf = 0; pf < 4; ++pf)
        acc[nf][pf] = __builtin_amdgcn_mfma_f32_16x16x32_bf16(a[nf], b[pf], acc[nf][pf], 0, 0, 0);
  }
  __syncthreads();  // all reads of h done before overwrite
#pragma unroll
  for (int nf = 0; nf < 4; ++nf) {
    int n0 = wid * 64 + nf * 16 + r8 * 4;
    f32x4 bv = *(const f32x4*)(bias + n0);
#pragma unroll
    for (int pf = 0; pf < 4; ++pf) {
      int pt = pf * 16 + l15;
      float z[4];
#pragma unroll
      for (int r = 0; r < 4; ++r) {
        float t = acc[nf][pf][r];
        if (ACT == 1) { t += bv[r]; t = t > 0.f ? t : 0.2f * t; }
        else { t = __sinf(fmaf(t, 30.0f, bv[r])); }
        z[r] = t;
      }
      int off = (pt * 1024 + n0 * 2) ^ ((pt & 7) << 4);
      *(unsigned long long*)(hb + off) = pk4(z[0], z[1], z[2], z[3]);
    }
  }
  __syncthreads();
}

__global__ __launch_bounds__(TPB, 4) void gmminr_main(
    const float* __restrict__ x,
    const float* __restrict__ b1, const float* __restrict__ bs2,
    const float* __restrict__ bs3, const float* __restrict__ bs4,
    const float* __restrict__ w5, const float* __restrict__ b5,
    const unsigned short* __restrict__ wf1, const unsigned short* __restrict__ wf2,
    const unsigned short* __restrict__ wf3, const unsigned short* __restrict__ wf4,
    const unsigned short* __restrict__ gff, const float* __restrict__ gp,
    float* __restrict__ out) {
  __shared__ char hb[PTS_PER_BLK * 1024 + 2048];
  float* part = (float*)(hb + PTS_PER_BLK * 1024);
  const int tid = threadIdx.x;
  const int lane = tid & 63;
  const int wid = tid >> 6;
  const int r8 = lane >> 4, l15 = lane & 15;
  const int pt0 = blockIdx.x * PTS_PER_BLK;

  // ---------------- stage: dens (cols 256..383), pe (128..175), pad (176..191)
  {
    const int pt = tid >> 3;
    const int q = tid & 7;
    const int gpt = pt0 + pt;
    const float X = x[gpt * 3 + 0], Y = x[gpt * 3 + 1], Z = x[gpt * 3 + 2];
    const int ps = (pt & 7) << 4;
    const int pb = pt * 1024;
#pragma unroll
    for (int j = 0; j < 16; j += 4) {
      float d4[4];
#pragma unroll
      for (int e = 0; e < 4; ++e) {
        const float* P = gp + (q * 16 + j + e) * 8;
        float dx = X - P[0], dy = Y - P[1], dz = Z - P[2];
        float m = fmaf(dx * dx, P[3], fmaf(dy * dy, P[4], dz * dz * P[5]));
        d4[e] = P[6] * __expf(-0.5f * m);
      }
      int off = (pb + 512 + q * 32 + j * 2) ^ ps;
      *(unsigned long long*)(hb + off) = pk4(d4[0], d4[1], d4[2], d4[3]);
    }
    // positional encoding: freq index le = q; cols 128+6q.. = [sx,sy,sz,cx,cy,cz]
    float fr = 3.14159265358979323846f * (float)(1 << q);
    float sx = __sinf(fr * X), sy = __sinf(fr * Y), sz2 = __sinf(fr * Z);
    float cx = __cosf(fr * X), cy = __cosf(fr * Y), cz = __cosf(fr * Z);
    int base = pb + 256 + 12 * q;
    *(unsigned int*)(hb + ((base + 0) ^ ps)) = pklo(sx, sy);
    *(unsigned int*)(hb + ((base + 4) ^ ps)) = pklo(sz2, cx);
    *(unsigned int*)(hb + ((base + 8) ^ ps)) = pklo(cy, cz);
    // zero pad cols 176..191
    *(unsigned int*)(hb + ((pb + 352 + 4 * q) ^ ps)) = 0u;
  }
  __syncthreads();

  // ---------------- feat = dens @ gfeat^T -> cols 0..127 (wave = 16 F-rows x 64 pts)
  {
    f32x4 facc[4];
#pragma unroll
    for (int pf = 0; pf < 4; ++pf) facc[pf] = (f32x4){0.f, 0.f, 0.f, 0.f};
    const unsigned short* gbase = gff + wid * 4 * 512 + lane * 8;
#pragma unroll
    for (int kb = 0; kb < 4; ++kb) {
      bf16x8 a = *(const bf16x8*)(gbase + kb * 512);
#pragma unroll
      for (int pf = 0; pf < 4; ++pf) {
        int pt = pf * 16 + l15;
        int off = (pt * 1024 + 512 + kb * 64 + r8 * 16) ^ ((pt & 7) << 4);
        bf16x8 b = *(const bf16x8*)(hb + off);
        facc[pf] = __builtin_amdgcn_mfma_f32_16x16x32_bf16(a, b, facc[pf], 0, 0, 0);
      }
    }
    // write cols 0..127 (disjoint from dens cols 256..383 still being read) — no barrier
    int f0 = wid * 16 + r8 * 4;
#pragma unroll
    for (int pf = 0; pf < 4; ++pf) {
      int pt = pf * 16 + l15;
      int off = (pt * 1024 + f0 * 2) ^ ((pt & 7) << 4);
      *(unsigned long long*)(hb + off) = pk4(facc[pf][0], facc[pf][1], facc[pf][2], facc[pf][3]);
    }
  }
  __syncthreads();

  // ---------------- MLP layers 1..3
  mlp_layer<6, 1>(wf1, b1, hb, lane, wid);     // 176(pad192)->512, lrelu
  mlp_layer<16, 2>(wf2, bs2, hb, lane, wid);   // sin(30x)
  mlp_layer<16, 2>(wf3, bs3, hb, lane, wid);

  // ---------------- layer 4 (sin) fused with final dot(w5) — no LDS round trip
  {
    f32x4 acc[4][4];
#pragma unroll
    for (int a0 = 0; a0 < 4; ++a0)
#pragma unroll
      for (int b0 = 0; b0 < 4; ++b0)
        acc[a0][b0] = (f32x4){0.f, 0.f, 0.f, 0.f};
    const unsigned short* wbase = wf4 + wid * 4 * 16 * 512 + lane * 8;
#pragma unroll 2
    for (int kb = 0; kb < 16; ++kb) {
      bf16x8 a[4];
#pragma unroll
      for (int nf = 0; nf < 4; ++nf)
        a[nf] = *(const bf16x8*)(wbase + (nf * 16 + kb) * 512);
#pragma unroll
      for (int pf = 0; pf < 4; ++pf) {
        int pt = pf * 16 + l15;
        int off = (pt * 1024 + kb * 64 + r8 * 16) ^ ((pt & 7) << 4);
        bf16x8 b = *(const bf16x8*)(hb + off);
#pragma unroll
        for (int nf = 0; nf < 4; ++nf)
          acc[nf][pf] = __builtin_amdgcn_mfma_f32_16x16x32_bf16(a[nf], b, acc[nf][pf], 0, 0, 0);
      }
    }
#pragma unroll
    for (int pf = 0; pf < 4; ++pf) {
      float s = 0.f;
#pragma unroll
      for (int nf = 0; nf < 4; ++nf) {
        int n0 = wid * 64 + nf * 16 + r8 * 4;
        f32x4 bv = *(const f32x4*)(bs4 + n0);
        f32x4 wv = *(const f32x4*)(w5 + n0);
#pragma unroll
        for (int r = 0; r < 4; ++r)
          s += __sinf(fmaf(acc[nf][pf][r], 30.0f, bv[r])) * wv[r];
      }
      // sum across the 4 r8 groups (same l15 = same point)
      s += __shfl_xor(s, 16);
      s += __shfl_xor(s, 32);
      if (lane < 16) part[(pf * 16 + l15) * 8 + wid] = s;
    }
  }
  __syncthreads();
  if (tid < PTS_PER_BLK) {
    const f32x4* pp = (const f32x4*)part;
    f32x4 a = pp[tid * 2], b = pp[tid * 2 + 1];
    out[pt0 + tid] = a[0] + a[1] + a[2] + a[3] + b[0] + b[1] + b[2] + b[3] + b5[0];
  }
}

extern "C" void kernel_launch(void* const* d_in, const int* in_sizes, int n_in,
                              void* d_out, int out_size, void* d_ws, size_t ws_size,
                              hipStream_t stream) {
  const float* x   = (const float*)d_in[0];
  const float* cen = (const float*)d_in[1];
  const float* cov = (const float*)d_in[2];
  const float* gfe = (const float*)d_in[3];
  const float* W1  = (const float*)d_in[4];
  const float* b1  = (const float*)d_in[5];
  const float* W2  = (const float*)d_in[6];
  const float* b2  = (const float*)d_in[7];
  const float* W3  = (const float*)d_in[8];
  const float* b3  = (const float*)d_in[9];
  const float* W4  = (const float*)d_in[10];
  const float* b4  = (const float*)d_in[11];
  const float* W5  = (const float*)d_in[12];
  const float* b5  = (const float*)d_in[13];
  float* out = (float*)d_out;

  char* ws = (char*)d_ws;
  unsigned short* wf1 = (unsigned short*)(ws);             // 32*6*512  el = 192KB
  unsigned short* wf2 = (unsigned short*)(ws + 196608);    // 32*16*512 el = 512KB
  unsigned short* wf3 = (unsigned short*)(ws + 720896);
  unsigned short* wf4 = (unsigned short*)(ws + 1245184);
  unsigned short* gff = (unsigned short*)(ws + 1769472);   // 8*4*512 el = 32KB
  float* gp  = (float*)(ws + 1802240);                     // 128*8 f32 = 4KB
  float* bs2 = (float*)(ws + 1806336);                     // 512 f32 (x30)
  float* bs3 = (float*)(ws + 1808384);
  float* bs4 = (float*)(ws + 1810432);

  prep_w<<<384, 256, 0, stream>>>(W1, wf1, 176, 6, 0, 512, 98304);
  prep_w<<<1024, 256, 0, stream>>>(W2, wf2, 512, 16, 0, 512, 262144);
  prep_w<<<1024, 256, 0, stream>>>(W3, wf3, 512, 16, 0, 512, 262144);
  prep_w<<<1024, 256, 0, stream>>>(W4, wf4, 512, 16, 0, 512, 262144);
  prep_w<<<64, 256, 0, stream>>>(gfe, gff, 128, 4, 1, 128, 16384);
  prep_gauss<<<1, 128, 0, stream>>>(cen, cov, gp);
  prep_scale<<<2, 256, 0, stream>>>(b2, bs2, 512);
  prep_scale<<<2, 256, 0, stream>>>(b3, bs3, 512);
  prep_scale<<<2, 256, 0, stream>>>(b4, bs4, 512);

  gmminr_main<<<NBLK, TPB, 0, stream>>>(x, b1, bs2, bs3, bs4, W5, b5,
                                        wf1, wf2, wf3, wf4, gff, gp, out);
}